// Round 2
// baseline (571.826 us; speedup 1.0000x reference)
//
#include <hip/hip_runtime.h>

#define B 32
#define C 512
#define HW 4096            // 64*64
#define K 256              // int(0.5 * C)
// spatial mean (1/HW) folded with mask mean (1/(B*K)): 1/(4096*8192) = 2^-25, exact
#define INV_SCALE (1.f / 33554432.f)

typedef float f4_t __attribute__((ext_vector_type(4)));

__inline__ __device__ float wave_reduce(float v) {
    #pragma unroll
    for (int o = 32; o > 0; o >>= 1) v += __shfl_down(v, o, 64);
    return v;
}

// Pass A: one block per (b,c) plane, read TARGETS only (256 MB total).
// Want tgt resident in L3 for pass C -> regular (cached) loads.
__global__ __launch_bounds__(256) void norm_pass(
        const float* __restrict__ tgt, float* __restrict__ norm2) {
    const int plane = blockIdx.x;                 // b*C + c
    const float4* __restrict__ tg4 = (const float4*)(tgt + (size_t)plane * HW);
    float t2 = 0.f;
    #pragma unroll
    for (int i = 0; i < 4; ++i) {                 // 1024 float4 / 256 threads
        const float4 t = tg4[threadIdx.x + i * 256];
        t2 += t.x * t.x + t.y * t.y + t.z * t.z + t.w * t.w;
    }
    __shared__ float s4[4];
    t2 = wave_reduce(t2);
    const int lane = threadIdx.x & 63, wid = threadIdx.x >> 6;
    if (lane == 0) s4[wid] = t2;
    __syncthreads();
    if (threadIdx.x == 0) norm2[plane] = s4[0] + s4[1] + s4[2] + s4[3];
}

// Pass B: one block per batch. Exact top-k by rank (jax tie-break: equal norm
// -> lower channel index wins). Ranks of kept channels are 0..K-1 distinct, so
// rank doubles as the compact-list slot. Also zeroes d_out for pass C atomics.
__global__ __launch_bounds__(C) void topk_select(
        const float* __restrict__ norm2, int* __restrict__ keep,
        float* __restrict__ out) {
    __shared__ float sn[C];
    const int b = blockIdx.x, c = threadIdx.x;
    sn[c] = norm2[b * C + c];
    if (b == 0 && c == 0) out[0] = 0.f;
    __syncthreads();
    const float my = sn[c];
    int rank = 0;
    #pragma unroll 8
    for (int j = 0; j < C; ++j) {
        const float o = sn[j];
        rank += (o > my) || (o == my && j < c);
    }
    if (rank < K) keep[b * K + rank] = c;
}

// Pass C: one block per KEPT plane (B*K = 8192 blocks). Reads 128 MB of in
// (nontemporal: single-use, don't evict tgt from L3) + 128 MB of tgt
// (hopefully L3-resident from pass A). One scaled atomicAdd per block.
__global__ __launch_bounds__(256) void masked_ssd(
        const float* __restrict__ in, const float* __restrict__ tgt,
        const int* __restrict__ keep, float* __restrict__ out) {
    const int i = blockIdx.x;
    const int b = i >> 8;                         // i / K, K=256
    const int c = keep[i];
    const size_t base = (size_t)(b * C + c) * HW;
    const f4_t* __restrict__ in4 = (const f4_t*)(in + base);
    const float4* __restrict__ tg4 = (const float4*)(tgt + base);
    float d2 = 0.f;
    #pragma unroll
    for (int k = 0; k < 4; ++k) {
        const int j = threadIdx.x + k * 256;
        const f4_t  a = __builtin_nontemporal_load(in4 + j);
        const float4 t = tg4[j];
        const float dx = a.x - t.x, dy = a.y - t.y, dz = a.z - t.z, dw = a.w - t.w;
        d2 += dx * dx + dy * dy + dz * dz + dw * dw;
    }
    __shared__ float s4[4];
    d2 = wave_reduce(d2);
    const int lane = threadIdx.x & 63, wid = threadIdx.x >> 6;
    if (lane == 0) s4[wid] = d2;
    __syncthreads();
    if (threadIdx.x == 0)
        atomicAdd(out, (s4[0] + s4[1] + s4[2] + s4[3]) * INV_SCALE);
}

extern "C" void kernel_launch(void* const* d_in, const int* in_sizes, int n_in,
                              void* d_out, int out_size, void* d_ws, size_t ws_size,
                              hipStream_t stream) {
    const float* in  = (const float*)d_in[0];
    const float* tgt = (const float*)d_in[1];
    float* out = (float*)d_out;

    float* norm2 = (float*)d_ws;            // B*C floats
    int*   keep  = (int*)(norm2 + B * C);   // B*K ints

    norm_pass<<<B * C, 256, 0, stream>>>(tgt, norm2);
    topk_select<<<B, C, 0, stream>>>(norm2, keep, out);
    masked_ssd<<<B * K, 256, 0, stream>>>(in, tgt, keep, out);
}

// Round 3
// 480.688 us; speedup vs baseline: 1.1896x; 1.1896x over previous
//
#include <hip/hip_runtime.h>

#define B 32
#define C 512
#define HW 4096            // 64*64
#define K 256              // int(0.5 * C)
// spatial mean (1/HW) folded with mask mean (1/(B*K)): 1/(4096*8192) = 2^-25, exact
#define INV_SCALE (1.f / 33554432.f)

typedef float f4_t __attribute__((ext_vector_type(4)));

__inline__ __device__ float wave_reduce(float v) {
    #pragma unroll
    for (int o = 32; o > 0; o >>= 1) v += __shfl_down(v, o, 64);
    return v;
}

// Kernel 1: one block per (b,c) plane, fused single pass over BOTH tensors
// (512 MB total, the algorithmic floor). Nontemporal loads: data is
// single-use and 2x the L3 size — don't pollute L2/L3 on the way through.
__global__ __launch_bounds__(256) void plane_reduce(
        const float* __restrict__ in, const float* __restrict__ tgt,
        float* __restrict__ norm2, float* __restrict__ ssd) {
    const int plane = blockIdx.x;                 // b*C + c
    const size_t base = (size_t)plane * HW;
    const f4_t* __restrict__ in4 = (const f4_t*)(in  + base);
    const f4_t* __restrict__ tg4 = (const f4_t*)(tgt + base);

    float t2 = 0.f, d2 = 0.f;
    #pragma unroll
    for (int i = 0; i < 4; ++i) {                 // 1024 float4 / 256 threads
        const int j = threadIdx.x + i * 256;
        const f4_t a = __builtin_nontemporal_load(in4 + j);
        const f4_t t = __builtin_nontemporal_load(tg4 + j);
        const float dx = a.x - t.x, dy = a.y - t.y, dz = a.z - t.z, dw = a.w - t.w;
        t2 += t.x * t.x + t.y * t.y + t.z * t.z + t.w * t.w;
        d2 += dx * dx + dy * dy + dz * dz + dw * dw;
    }

    t2 = wave_reduce(t2);
    d2 = wave_reduce(d2);

    __shared__ float st[4], sd[4];
    const int lane = threadIdx.x & 63, wid = threadIdx.x >> 6;
    if (lane == 0) { st[wid] = t2; sd[wid] = d2; }
    __syncthreads();
    if (threadIdx.x == 0) {
        norm2[plane] = st[0] + st[1] + st[2] + st[3];
        ssd[plane]   = sd[0] + sd[1] + sd[2] + sd[3];
    }
}

// Kernel 2 (fused topk + masked sum + finalize): one block per batch.
// Exact top-k by rank with jax tie-breaking (equal norm -> lower index).
// Masked block-sum of ssd, then one scaled atomicAdd into out[0]
// (zeroed by hipMemsetAsync before this kernel).
__global__ __launch_bounds__(C) void topk_mask_sum(
        const float* __restrict__ norm2, const float* __restrict__ ssd,
        float* __restrict__ out) {
    __shared__ float sn[C];
    __shared__ float red[C / 64];
    const int b = blockIdx.x, c = threadIdx.x;
    sn[c] = norm2[b * C + c];
    __syncthreads();

    const float my = sn[c];
    int rank = 0;
    #pragma unroll 8
    for (int j = 0; j < C; ++j) {
        const float o = sn[j];
        rank += (o > my) || (o == my && j < c);
    }
    float v = (rank < K) ? ssd[b * C + c] : 0.f;

    v = wave_reduce(v);
    const int lane = c & 63, wid = c >> 6;
    if (lane == 0) red[wid] = v;
    __syncthreads();
    if (c == 0) {
        float s = 0.f;
        #pragma unroll
        for (int w = 0; w < C / 64; ++w) s += red[w];
        atomicAdd(out, s * INV_SCALE);
    }
}

extern "C" void kernel_launch(void* const* d_in, const int* in_sizes, int n_in,
                              void* d_out, int out_size, void* d_ws, size_t ws_size,
                              hipStream_t stream) {
    const float* in  = (const float*)d_in[0];
    const float* tgt = (const float*)d_in[1];
    float* out = (float*)d_out;

    float* norm2 = (float*)d_ws;            // B*C floats
    float* ssd   = norm2 + B * C;           // B*C floats

    hipMemsetAsync(out, 0, sizeof(float), stream);
    plane_reduce<<<B * C, 256, 0, stream>>>(in, tgt, norm2, ssd);
    topk_mask_sum<<<B, C, 0, stream>>>(norm2, ssd, out);
}